// Round 10
// baseline (45.126 us; speedup 1.0000x reference)
//
#include <hip/hip_runtime.h>

typedef unsigned short ushort8v __attribute__((ext_vector_type(8)));
typedef float float4v __attribute__((ext_vector_type(4)));

namespace {
constexpr int kB = 2, kC = 256, kH = 100, kW = 152;
constexpr int kN = 1000;
constexpr int kPH = 7, kPW = 7, kSR = 2;
constexpr float kScale = 0.0625f;
constexpr int kHW = kH * kW;                 // 15200
constexpr int kWC = kW * kC;                 // NHWC row stride (elems)
constexpr int kBins = kPH * kPW;             // 49
constexpr int kOutPerRoi = kC * kBins;       // 12544
constexpr int kCh = 128;                     // channels per block (half)
constexpr int kStrideE = 132;                // bf16 elems per bin (128 + pad)
constexpr int kNY = kPH * kSR;               // 14
constexpr int kNX = kPW * kSR;               // 14
constexpr int kThreads = 256;                // 4 waves
}

__device__ __forceinline__ float b2f(unsigned short u) {
  union { unsigned int i; float f; } x; x.i = ((unsigned int)u) << 16; return x.f;
}
__device__ __forceinline__ unsigned short f2b(float f) {
  union { float f; unsigned int i; } x; x.f = f;
  return (unsigned short)((x.i + 0x7FFFu + ((x.i >> 16) & 1u)) >> 16);  // RNE
}

// (B,C,H,W) f32 -> (B,H*W,C) bf16, tiled 32x32 transpose
__global__ __launch_bounds__(256) void transpose_k(const float* __restrict__ in,
                                                   unsigned short* __restrict__ out) {
  __shared__ float tile[32][33];
  const int b = blockIdx.z;
  const int hw0 = blockIdx.x * 32;
  const int c0 = blockIdx.y * 32;
  const int tx = threadIdx.x;   // 0..7  (x4 floats)
  const int ty = threadIdx.y;   // 0..31
  const float4 v = *(const float4*)(in + (size_t)b * kC * kHW +
                                    (size_t)(c0 + ty) * kHW + hw0 + tx * 4);
  tile[tx * 4 + 0][ty] = v.x;
  tile[tx * 4 + 1][ty] = v.y;
  tile[tx * 4 + 2][ty] = v.z;
  tile[tx * 4 + 3][ty] = v.w;
  __syncthreads();
  unsigned int lo = (unsigned int)f2b(tile[ty][tx * 4 + 0]) |
                    ((unsigned int)f2b(tile[ty][tx * 4 + 1]) << 16);
  unsigned int hi = (unsigned int)f2b(tile[ty][tx * 4 + 2]) |
                    ((unsigned int)f2b(tile[ty][tx * 4 + 3]) << 16);
  unsigned int* dst = (unsigned int*)(out + (size_t)b * kHW * kC +
                                      (size_t)(hw0 + ty) * kC + c0 + tx * 4);
  dst[0] = lo;
  dst[1] = hi;
}

// 2 blocks per ROI (channel halves); 4 waves; wave strides bins.
// lane = (c4 = x-column 0..3) * 16 + (octet 0..15): 4 sample columns x 16
// channel-octets, 16B per lane -> ~1KB per wave load instruction.
__global__ __launch_bounds__(kThreads, 8) void roialign_k(
    const unsigned short* __restrict__ ft, const float* __restrict__ rois,
    float* __restrict__ out) {
  __shared__ unsigned short sOut[kBins * kStrideE];  // ~12.9 KB
  __shared__ int sYlo[kNY], sXlo[kNX];
  __shared__ float sHy[kNY], sLy[kNY], sHx[kNX], sLx[kNX];
  __shared__ int sB;

  const int n = blockIdx.x >> 1;
  const int ch0 = (blockIdx.x & 1) << 7;   // 0 or 128
  const int t = threadIdx.x;

  if (t < kNY + kNX) {
    const bool isX = t >= kNY;
    const int i = isX ? t - kNY : t;
    const float x1 = rois[n * 5 + 1] * kScale;
    const float y1 = rois[n * 5 + 2] * kScale;
    const float x2 = rois[n * 5 + 3] * kScale;
    const float y2 = rois[n * 5 + 4] * kScale;
    const float roiw = fmaxf(x2 - x1, 1.0f);
    const float roih = fmaxf(y2 - y1, 1.0f);
    const float start = isX ? x1 : y1;
    const float binsz = isX ? (roiw / kPW) : (roih / kPH);
    const float size = isX ? (float)kW : (float)kH;
    const int p = i / kSR, s = i % kSR;
    const float c = start + p * binsz + (s + 0.5f) * binsz / kSR;
    const bool valid = (c > -1.0f) && (c < size);
    const float cc = fminf(fmaxf(c, 0.0f), size - 1.0f);
    const float lo = fminf(floorf(cc), size - 2.0f);
    const float fr = cc - lo;
    // fold the 1/(SR*SR)=0.25 average into the weights (0.5 per axis)
    const float wHi = valid ? (1.0f - fr) * 0.5f : 0.0f;
    const float wLo = valid ? fr * 0.5f : 0.0f;
    if (isX) { sXlo[i] = (int)lo; sHx[i] = wHi; sLx[i] = wLo; }
    else     { sYlo[i] = (int)lo; sHy[i] = wHi; sLy[i] = wLo; }
  }
  if (t == 0) sB = (int)rois[n * 5 + 0];
  __syncthreads();

  const int wave = t >> 6;       // 0..3
  const int lane = t & 63;
  const int c4 = lane >> 4;      // 0..3: which sample column
  const int octet = lane & 15;   // channel octet within the 128-ch half
  const int cpar = c4 & 1;       // 0: x-lo of pair, 1: x-hi
  const int csel = c4 >> 1;      // 0: sample 0 pair, 1: sample 1 pair
  const unsigned short* fb = ft + (size_t)sB * kHW * kC + ch0 + octet * 8;
  unsigned int* s32 = (unsigned int*)sOut;

  for (int bin = wave; bin < kBins; bin += 4) {
    const int ph = bin / kPW, pw = bin - (bin / kPW) * kPW;
    // y-state for this bin row
    const int iy0 = ph * kSR, iy1 = iy0 + 1;
    const int rA = sYlo[iy0] * kWC;
    const int rB = sYlo[iy1] * kWC;
    const float hy0 = sHy[iy0], ly0 = sLy[iy0];
    const float hy1 = sHy[iy1], ly1 = sLy[iy1];
    // this lane's x column
    const int ix = pw * kSR + csel;
    const int xo = (sXlo[ix] + cpar) * kC;
    const float wx = cpar ? sLx[ix] : sHx[ix];
    const ushort8v v0 = *(const ushort8v*)(fb + rA + xo);        // y s0 top
    const ushort8v v1 = *(const ushort8v*)(fb + rA + kWC + xo);  // y s0 bot
    const ushort8v v2 = *(const ushort8v*)(fb + rB + xo);        // y s1 top
    const ushort8v v3 = *(const ushort8v*)(fb + rB + kWC + xo);  // y s1 bot
    float acc[8];
#pragma unroll
    for (int k = 0; k < 8; ++k)
      acc[k] = wx * (hy0 * b2f(v0[k]) + ly0 * b2f(v1[k]) +
                     hy1 * b2f(v2[k]) + ly1 * b2f(v3[k]));
    // merge 4 columns: butterfly over lane bits 4 and 5
#pragma unroll
    for (int k = 0; k < 8; ++k) acc[k] += __shfl_xor(acc[k], 16);
#pragma unroll
    for (int k = 0; k < 8; ++k) acc[k] += __shfl_xor(acc[k], 32);
    // each of the 4 duplicate lanes stores a different channel pair
    const float aLo = (c4 == 0) ? acc[0] : (c4 == 1) ? acc[2] : (c4 == 2) ? acc[4] : acc[6];
    const float aHi = (c4 == 0) ? acc[1] : (c4 == 1) ? acc[3] : (c4 == 2) ? acc[5] : acc[7];
    const unsigned int wrd = (unsigned int)f2b(aLo) | ((unsigned int)f2b(aHi) << 16);
    s32[bin * (kStrideE / 2) + octet * 4 + c4] = wrd;
  }
  __syncthreads();

  // coalesced non-temporal float4 write of this block's (128,PH,PW) region
  float4v* ob4 = (float4v*)(out + (size_t)n * kOutPerRoi + ch0 * kBins);
  for (int q = t; q < kCh * kBins / 4; q += kThreads) {
    const int f = q * 4;
    const int c0 = (f + 0) / kBins, b0 = (f + 0) - c0 * kBins;
    const int c1 = (f + 1) / kBins, b1 = (f + 1) - c1 * kBins;
    const int c2 = (f + 2) / kBins, b2 = (f + 2) - c2 * kBins;
    const int c3 = (f + 3) / kBins, b3 = (f + 3) - c3 * kBins;
    float4v v;
    v.x = b2f(sOut[b0 * kStrideE + c0]);
    v.y = b2f(sOut[b1 * kStrideE + c1]);
    v.z = b2f(sOut[b2 * kStrideE + c2]);
    v.w = b2f(sOut[b3 * kStrideE + c3]);
    __builtin_nontemporal_store(v, &ob4[q]);
  }
}

extern "C" void kernel_launch(void* const* d_in, const int* in_sizes, int n_in,
                              void* d_out, int out_size, void* d_ws, size_t ws_size,
                              hipStream_t stream) {
  const float* feat = (const float*)d_in[0];
  const float* rois = (const float*)d_in[1];
  float* out = (float*)d_out;
  unsigned short* ft = (unsigned short*)d_ws;  // kB*kHW*kC*2 = 15.6 MB scratch

  hipLaunchKernelGGL(transpose_k, dim3(kHW / 32, kC / 32, kB), dim3(8, 32), 0,
                     stream, feat, ft);
  hipLaunchKernelGGL(roialign_k, dim3(kN * 2), dim3(kThreads), 0, stream, ft,
                     rois, out);
}

// Round 11
// 45.101 us; speedup vs baseline: 1.0006x; 1.0006x over previous
//
#include <hip/hip_runtime.h>

typedef unsigned short ushort8v __attribute__((ext_vector_type(8)));
typedef float float4v __attribute__((ext_vector_type(4)));

namespace {
constexpr int kB = 2, kC = 256, kH = 100, kW = 152;
constexpr int kN = 1000;
constexpr int kPH = 7, kPW = 7, kSR = 2;
constexpr float kScale = 0.0625f;
constexpr int kHW = kH * kW;                 // 15200
constexpr int kBins = kPH * kPW;             // 49
constexpr int kOutPerRoi = kC * kBins;       // 12544
constexpr int kStrideE = 260;                // bf16 elems; 130 u32 words
constexpr int kNY = kPH * kSR;               // 14
constexpr int kNX = kPW * kSR;               // 14
constexpr int kThreads = 512;
}

__device__ __forceinline__ float b2f(unsigned short u) {
  union { unsigned int i; float f; } x; x.i = ((unsigned int)u) << 16; return x.f;
}
__device__ __forceinline__ unsigned short f2b(float f) {
  union { float f; unsigned int i; } x; x.f = f;
  return (unsigned short)((x.i + 0x7FFFu + ((x.i >> 16) & 1u)) >> 16);  // RNE
}

// (B,C,H,W) f32 -> (B,H*W,C) bf16, tiled 32x32 transpose; NT read (read-once)
__global__ __launch_bounds__(256) void transpose_k(const float* __restrict__ in,
                                                   unsigned short* __restrict__ out) {
  __shared__ float tile[32][33];
  const int b = blockIdx.z;
  const int hw0 = blockIdx.x * 32;
  const int c0 = blockIdx.y * 32;
  const int tx = threadIdx.x;   // 0..7  (x4 floats)
  const int ty = threadIdx.y;   // 0..31
  const float4v v = __builtin_nontemporal_load(
      (const float4v*)(in + (size_t)b * kC * kHW + (size_t)(c0 + ty) * kHW +
                       hw0 + tx * 4));
  tile[tx * 4 + 0][ty] = v.x;
  tile[tx * 4 + 1][ty] = v.y;
  tile[tx * 4 + 2][ty] = v.z;
  tile[tx * 4 + 3][ty] = v.w;
  __syncthreads();
  unsigned int lo = (unsigned int)f2b(tile[ty][tx * 4 + 0]) |
                    ((unsigned int)f2b(tile[ty][tx * 4 + 1]) << 16);
  unsigned int hi = (unsigned int)f2b(tile[ty][tx * 4 + 2]) |
                    ((unsigned int)f2b(tile[ty][tx * 4 + 3]) << 16);
  unsigned int* dst = (unsigned int*)(out + (size_t)b * kHW * kC +
                                      (size_t)(hw0 + ty) * kC + c0 + tx * 4);
  dst[0] = lo;
  dst[1] = hi;
}

// one block per ROI; 8 waves; per bin: lanes 0-31 = x-lo corner, 32-63 = x-hi,
// each lane 8 channels via one 16B load -> 1KB contiguous per wave instruction
__global__ __launch_bounds__(kThreads, 8) void roialign_k(
    const unsigned short* __restrict__ ft, const float* __restrict__ rois,
    float* __restrict__ out) {
  __shared__ unsigned short sOut[kBins * kStrideE];  // ~24.9 KB
  __shared__ int sYlo[kNY], sXlo[kNX];
  __shared__ float sHy[kNY], sLy[kNY], sHx[kNX], sLx[kNX];
  __shared__ int sB;

  const int n = blockIdx.x;
  const int t = threadIdx.x;

  if (t < kNY + kNX) {
    const bool isX = t >= kNY;
    const int i = isX ? t - kNY : t;
    const float x1 = rois[n * 5 + 1] * kScale;
    const float y1 = rois[n * 5 + 2] * kScale;
    const float x2 = rois[n * 5 + 3] * kScale;
    const float y2 = rois[n * 5 + 4] * kScale;
    const float roiw = fmaxf(x2 - x1, 1.0f);
    const float roih = fmaxf(y2 - y1, 1.0f);
    const float start = isX ? x1 : y1;
    const float binsz = isX ? (roiw / kPW) : (roih / kPH);
    const float size = isX ? (float)kW : (float)kH;
    const int p = i / kSR, s = i % kSR;
    const float c = start + p * binsz + (s + 0.5f) * binsz / kSR;
    const bool valid = (c > -1.0f) && (c < size);
    const float cc = fminf(fmaxf(c, 0.0f), size - 1.0f);
    const float lo = fminf(floorf(cc), size - 2.0f);
    const float fr = cc - lo;
    // fold the 1/(SR*SR)=0.25 average into the weights (0.5 per axis)
    const float wHi = valid ? (1.0f - fr) * 0.5f : 0.0f;
    const float wLo = valid ? fr * 0.5f : 0.0f;
    if (isX) { sXlo[i] = (int)lo; sHx[i] = wHi; sLx[i] = wLo; }
    else     { sYlo[i] = (int)lo; sHy[i] = wHi; sLy[i] = wLo; }
  }
  if (t == 0) sB = (int)rois[n * 5 + 0];
  __syncthreads();

  const int wave = t >> 6;       // 0..7
  const int lane = t & 63;
  const int half = lane >> 5;    // 0: x-lo corner, 1: x-hi corner
  const int sub = lane & 31;     // channel octet index
  const unsigned short* fb = ft + (size_t)sB * kHW * kC + sub * 8;
  unsigned int* s32 = (unsigned int*)sOut;

  for (int bin = wave; bin < kBins; bin += 8) {
    const int ph = bin / kPW, pw = bin % kPW;
    float acc[8] = {0.f, 0.f, 0.f, 0.f, 0.f, 0.f, 0.f, 0.f};
#pragma unroll
    for (int sy = 0; sy < kSR; ++sy) {
      const int iy = ph * kSR + sy;
      const int ylo = sYlo[iy];
      const float hy = sHy[iy], ly = sLy[iy];
#pragma unroll
      for (int sx = 0; sx < kSR; ++sx) {
        const int ix = pw * kSR + sx;
        const int xlo = sXlo[ix];
        const float hxs = half ? sLx[ix] : sHx[ix];   // this half's x-weight
        const float wTop = hy * hxs, wBot = ly * hxs;
        const unsigned short* p0 = fb + ((size_t)(ylo * kW + xlo + half)) * kC;
        const ushort8v v0 = *(const ushort8v*)(p0);            // row ylo
        const ushort8v v1 = *(const ushort8v*)(p0 + kW * kC);  // row ylo+1
#pragma unroll
        for (int k = 0; k < 8; ++k)
          acc[k] += wTop * b2f(v0[k]) + wBot * b2f(v1[k]);
      }
    }
    // merge the two corner-halves: butterfly across lane^32
#pragma unroll
    for (int k = 0; k < 8; ++k) acc[k] += __shfl_xor(acc[k], 32);
    // lane stores 2 u32 words (4 channels), picked by half; 8B-aligned
    const int kBase = half * 4;
    const unsigned int wA = (unsigned int)f2b(acc[kBase + 0]) |
                            ((unsigned int)f2b(acc[kBase + 1]) << 16);
    const unsigned int wB = (unsigned int)f2b(acc[kBase + 2]) |
                            ((unsigned int)f2b(acc[kBase + 3]) << 16);
    const int wIdx = bin * (kStrideE / 2) + sub * 4 + half * 2;
    s32[wIdx + 0] = wA;
    s32[wIdx + 1] = wB;
  }
  __syncthreads();

  // coalesced non-temporal float4 write of this ROI's (C,PH,PW) block
  float4v* ob4 = (float4v*)(out + (size_t)n * kOutPerRoi);
  for (int q = t; q < kOutPerRoi / 4; q += kThreads) {
    const int f = q * 4;
    const int c0 = (f + 0) / kBins, b0 = (f + 0) - c0 * kBins;
    const int c1 = (f + 1) / kBins, b1 = (f + 1) - c1 * kBins;
    const int c2 = (f + 2) / kBins, b2 = (f + 2) - c2 * kBins;
    const int c3 = (f + 3) / kBins, b3 = (f + 3) - c3 * kBins;
    float4v v;
    v.x = b2f(sOut[b0 * kStrideE + c0]);
    v.y = b2f(sOut[b1 * kStrideE + c1]);
    v.z = b2f(sOut[b2 * kStrideE + c2]);
    v.w = b2f(sOut[b3 * kStrideE + c3]);
    __builtin_nontemporal_store(v, &ob4[q]);
  }
}

extern "C" void kernel_launch(void* const* d_in, const int* in_sizes, int n_in,
                              void* d_out, int out_size, void* d_ws, size_t ws_size,
                              hipStream_t stream) {
  const float* feat = (const float*)d_in[0];
  const float* rois = (const float*)d_in[1];
  float* out = (float*)d_out;
  unsigned short* ft = (unsigned short*)d_ws;  // kB*kHW*kC*2 = 15.6 MB scratch

  hipLaunchKernelGGL(transpose_k, dim3(kHW / 32, kC / 32, kB), dim3(8, 32), 0,
                     stream, feat, ft);
  hipLaunchKernelGGL(roialign_k, dim3(kN), dim3(kThreads), 0, stream, ft, rois, out);
}

// Round 12
// 42.933 us; speedup vs baseline: 1.0511x; 1.0505x over previous
//
#include <hip/hip_runtime.h>

typedef unsigned short ushort8v __attribute__((ext_vector_type(8)));
typedef float float4v __attribute__((ext_vector_type(4)));

namespace {
constexpr int kB = 2, kC = 256, kH = 100, kW = 152;
constexpr int kN = 1000;
constexpr int kPH = 7, kPW = 7, kSR = 2;
constexpr float kScale = 0.0625f;
constexpr int kHW = kH * kW;                 // 15200
constexpr int kBins = kPH * kPW;             // 49
constexpr int kOutPerRoi = kC * kBins;       // 12544
constexpr int kStrideE = 258;                // 129 u32 words (odd) -> all 32 banks
constexpr int kNY = kPH * kSR;               // 14
constexpr int kNX = kPW * kSR;               // 14
constexpr int kThreads = 512;
}

__device__ __forceinline__ float b2f(unsigned short u) {
  union { unsigned int i; float f; } x; x.i = ((unsigned int)u) << 16; return x.f;
}
__device__ __forceinline__ unsigned short f2b(float f) {
  union { float f; unsigned int i; } x; x.f = f;
  return (unsigned short)((x.i + 0x7FFFu + ((x.i >> 16) & 1u)) >> 16);  // RNE
}

// (B,C,H,W) f32 -> (B,H*W,C) bf16, tiled 32x32 transpose
__global__ __launch_bounds__(256) void transpose_k(const float* __restrict__ in,
                                                   unsigned short* __restrict__ out) {
  __shared__ float tile[32][33];
  const int b = blockIdx.z;
  const int hw0 = blockIdx.x * 32;
  const int c0 = blockIdx.y * 32;
  const int tx = threadIdx.x;   // 0..7  (x4 floats)
  const int ty = threadIdx.y;   // 0..31
  const float4 v = *(const float4*)(in + (size_t)b * kC * kHW +
                                    (size_t)(c0 + ty) * kHW + hw0 + tx * 4);
  tile[tx * 4 + 0][ty] = v.x;
  tile[tx * 4 + 1][ty] = v.y;
  tile[tx * 4 + 2][ty] = v.z;
  tile[tx * 4 + 3][ty] = v.w;
  __syncthreads();
  unsigned int lo = (unsigned int)f2b(tile[ty][tx * 4 + 0]) |
                    ((unsigned int)f2b(tile[ty][tx * 4 + 1]) << 16);
  unsigned int hi = (unsigned int)f2b(tile[ty][tx * 4 + 2]) |
                    ((unsigned int)f2b(tile[ty][tx * 4 + 3]) << 16);
  unsigned int* dst = (unsigned int*)(out + (size_t)b * kHW * kC +
                                      (size_t)(hw0 + ty) * kC + c0 + tx * 4);
  dst[0] = lo;
  dst[1] = hi;
}

// one block per ROI; 8 waves; per bin: lanes 0-31 = x-lo corner, 32-63 = x-hi,
// each lane 8 channels via one 16B load -> 1KB contiguous per wave instruction
__global__ __launch_bounds__(kThreads, 8) void roialign_k(
    const unsigned short* __restrict__ ft, const float* __restrict__ rois,
    float* __restrict__ out) {
  __shared__ unsigned short sOut[kBins * kStrideE];  // ~25.3 KB
  __shared__ int sYlo[kNY], sXlo[kNX];
  __shared__ float sHy[kNY], sLy[kNY], sHx[kNX], sLx[kNX];
  __shared__ int sB;

  const int n = blockIdx.x;
  const int t = threadIdx.x;

  if (t < kNY + kNX) {
    const bool isX = t >= kNY;
    const int i = isX ? t - kNY : t;
    const float x1 = rois[n * 5 + 1] * kScale;
    const float y1 = rois[n * 5 + 2] * kScale;
    const float x2 = rois[n * 5 + 3] * kScale;
    const float y2 = rois[n * 5 + 4] * kScale;
    const float roiw = fmaxf(x2 - x1, 1.0f);
    const float roih = fmaxf(y2 - y1, 1.0f);
    const float start = isX ? x1 : y1;
    const float binsz = isX ? (roiw / kPW) : (roih / kPH);
    const float size = isX ? (float)kW : (float)kH;
    const int p = i / kSR, s = i % kSR;
    const float c = start + p * binsz + (s + 0.5f) * binsz / kSR;
    const bool valid = (c > -1.0f) && (c < size);
    const float cc = fminf(fmaxf(c, 0.0f), size - 1.0f);
    const float lo = fminf(floorf(cc), size - 2.0f);
    const float fr = cc - lo;
    // fold the 1/(SR*SR)=0.25 average into the weights (0.5 per axis)
    const float wHi = valid ? (1.0f - fr) * 0.5f : 0.0f;
    const float wLo = valid ? fr * 0.5f : 0.0f;
    if (isX) { sXlo[i] = (int)lo; sHx[i] = wHi; sLx[i] = wLo; }
    else     { sYlo[i] = (int)lo; sHy[i] = wHi; sLy[i] = wLo; }
  }
  if (t == 0) sB = (int)rois[n * 5 + 0];
  __syncthreads();

  const int wave = t >> 6;       // 0..7
  const int lane = t & 63;
  const int half = lane >> 5;    // 0: x-lo corner, 1: x-hi corner
  const int sub = lane & 31;     // channel octet index
  const unsigned short* fb = ft + (size_t)sB * kHW * kC + sub * 8;
  unsigned int* s32 = (unsigned int*)sOut;

  for (int bin = wave; bin < kBins; bin += 8) {
    const int ph = bin / kPW, pw = bin % kPW;
    float acc[8] = {0.f, 0.f, 0.f, 0.f, 0.f, 0.f, 0.f, 0.f};
#pragma unroll
    for (int sy = 0; sy < kSR; ++sy) {
      const int iy = ph * kSR + sy;
      const int ylo = sYlo[iy];
      const float hy = sHy[iy], ly = sLy[iy];
#pragma unroll
      for (int sx = 0; sx < kSR; ++sx) {
        const int ix = pw * kSR + sx;
        const int xlo = sXlo[ix];
        const float hxs = half ? sLx[ix] : sHx[ix];   // this half's x-weight
        const float wTop = hy * hxs, wBot = ly * hxs;
        const unsigned short* p0 = fb + ((size_t)(ylo * kW + xlo + half)) * kC;
        const ushort8v v0 = *(const ushort8v*)(p0);            // row ylo
        const ushort8v v1 = *(const ushort8v*)(p0 + kW * kC);  // row ylo+1
#pragma unroll
        for (int k = 0; k < 8; ++k)
          acc[k] += wTop * b2f(v0[k]) + wBot * b2f(v1[k]);
      }
    }
    // merge the two corner-halves: butterfly across lane^32
#pragma unroll
    for (int k = 0; k < 8; ++k) acc[k] += __shfl_xor(acc[k], 32);
    // lane stores 2 u32 words (4 channels), picked by half
    const int kBase = half * 4;
    const unsigned int wA = (unsigned int)f2b(acc[kBase + 0]) |
                            ((unsigned int)f2b(acc[kBase + 1]) << 16);
    const unsigned int wB = (unsigned int)f2b(acc[kBase + 2]) |
                            ((unsigned int)f2b(acc[kBase + 3]) << 16);
    const int wIdx = bin * (kStrideE / 2) + sub * 4 + half * 2;
    s32[wIdx + 0] = wA;
    s32[wIdx + 1] = wB;
  }
  __syncthreads();

  // coalesced non-temporal float4 write of this ROI's (C,PH,PW) block
  float4v* ob4 = (float4v*)(out + (size_t)n * kOutPerRoi);
  for (int q = t; q < kOutPerRoi / 4; q += kThreads) {
    const int f = q * 4;
    const int c0 = (f + 0) / kBins, b0 = (f + 0) - c0 * kBins;
    const int c1 = (f + 1) / kBins, b1 = (f + 1) - c1 * kBins;
    const int c2 = (f + 2) / kBins, b2 = (f + 2) - c2 * kBins;
    const int c3 = (f + 3) / kBins, b3 = (f + 3) - c3 * kBins;
    float4v v;
    v.x = b2f(sOut[b0 * kStrideE + c0]);
    v.y = b2f(sOut[b1 * kStrideE + c1]);
    v.z = b2f(sOut[b2 * kStrideE + c2]);
    v.w = b2f(sOut[b3 * kStrideE + c3]);
    __builtin_nontemporal_store(v, &ob4[q]);
  }
}

extern "C" void kernel_launch(void* const* d_in, const int* in_sizes, int n_in,
                              void* d_out, int out_size, void* d_ws, size_t ws_size,
                              hipStream_t stream) {
  const float* feat = (const float*)d_in[0];
  const float* rois = (const float*)d_in[1];
  float* out = (float*)d_out;
  unsigned short* ft = (unsigned short*)d_ws;  // kB*kHW*kC*2 = 15.6 MB scratch

  hipLaunchKernelGGL(transpose_k, dim3(kHW / 32, kC / 32, kB), dim3(8, 32), 0,
                     stream, feat, ft);
  hipLaunchKernelGGL(roialign_k, dim3(kN), dim3(kThreads), 0, stream, ft, rois, out);
}

// Round 13
// 42.317 us; speedup vs baseline: 1.0664x; 1.0145x over previous
//
#include <hip/hip_runtime.h>

typedef unsigned short ushort8v __attribute__((ext_vector_type(8)));
typedef float float4v __attribute__((ext_vector_type(4)));

namespace {
constexpr int kB = 2, kC = 256, kH = 100, kW = 152;
constexpr int kN = 1000;
constexpr int kPH = 7, kPW = 7, kSR = 2;
constexpr float kScale = 0.0625f;
constexpr int kHW = kH * kW;                 // 15200
constexpr int kBins = kPH * kPW;             // 49
constexpr int kOutPerRoi = kC * kBins;       // 12544
constexpr int kStrideE = 258;                // 129 u32 words (odd) -> all 32 banks
constexpr int kNY = kPH * kSR;               // 14
constexpr int kNX = kPW * kSR;               // 14
constexpr int kThreads = 512;
}

__device__ __forceinline__ float b2f(unsigned short u) {
  union { unsigned int i; float f; } x; x.i = ((unsigned int)u) << 16; return x.f;
}
__device__ __forceinline__ unsigned short f2b(float f) {
  union { float f; unsigned int i; } x; x.f = f;
  return (unsigned short)((x.i + 0x7FFFu + ((x.i >> 16) & 1u)) >> 16);  // RNE
}

// (B,C,H,W) f32 -> (B,H*W,C) bf16. 32hw x 64c tile; store = 16B ushort8/thread.
__global__ __launch_bounds__(256) void transpose_k(const float* __restrict__ in,
                                                   unsigned short* __restrict__ out) {
  __shared__ float tile[64][33];
  const int b = blockIdx.z;
  const int hw0 = blockIdx.x * 32;
  const int c0 = blockIdx.y * 64;
  const int t = threadIdx.x;          // 0..255
  const int tx = t & 7;               // hw quad (x4 floats)
  const int ty = t >> 3;              // c row 0..31
  const float* src = in + (size_t)b * kC * kHW + hw0 + tx * 4;
#pragma unroll
  for (int h = 0; h < 2; ++h) {
    const int c = ty + h * 32;
    const float4 v = *(const float4*)(src + (size_t)(c0 + c) * kHW);
    tile[c][tx * 4 + 0] = v.x;
    tile[c][tx * 4 + 1] = v.y;
    tile[c][tx * 4 + 2] = v.z;
    tile[c][tx * 4 + 3] = v.w;
  }
  __syncthreads();
  const int hw = t >> 3;              // 0..31
  const int c8 = (t & 7) * 8;         // channel octet start
  ushort8v w;
#pragma unroll
  for (int j = 0; j < 8; ++j) w[j] = f2b(tile[c8 + j][hw]);
  *(ushort8v*)(out + (size_t)b * kHW * kC + (size_t)(hw0 + hw) * kC + c0 + c8) = w;
}

// one block per ROI; 8 waves; per bin: lanes 0-31 = x-lo corner, 32-63 = x-hi,
// each lane 8 channels via one 16B load -> 1KB contiguous per wave instruction
__global__ __launch_bounds__(kThreads, 8) void roialign_k(
    const unsigned short* __restrict__ ft, const float* __restrict__ rois,
    float* __restrict__ out) {
  __shared__ unsigned short sOut[kBins * kStrideE];  // ~25.3 KB
  __shared__ int sYlo[kNY], sXlo[kNX];
  __shared__ float sHy[kNY], sLy[kNY], sHx[kNX], sLx[kNX];
  __shared__ int sB;

  const int n = blockIdx.x;
  const int t = threadIdx.x;

  if (t < kNY + kNX) {
    const bool isX = t >= kNY;
    const int i = isX ? t - kNY : t;
    const float x1 = rois[n * 5 + 1] * kScale;
    const float y1 = rois[n * 5 + 2] * kScale;
    const float x2 = rois[n * 5 + 3] * kScale;
    const float y2 = rois[n * 5 + 4] * kScale;
    const float roiw = fmaxf(x2 - x1, 1.0f);
    const float roih = fmaxf(y2 - y1, 1.0f);
    const float start = isX ? x1 : y1;
    const float binsz = isX ? (roiw / kPW) : (roih / kPH);
    const float size = isX ? (float)kW : (float)kH;
    const int p = i / kSR, s = i % kSR;
    const float c = start + p * binsz + (s + 0.5f) * binsz / kSR;
    const bool valid = (c > -1.0f) && (c < size);
    const float cc = fminf(fmaxf(c, 0.0f), size - 1.0f);
    const float lo = fminf(floorf(cc), size - 2.0f);
    const float fr = cc - lo;
    // fold the 1/(SR*SR)=0.25 average into the weights (0.5 per axis)
    const float wHi = valid ? (1.0f - fr) * 0.5f : 0.0f;
    const float wLo = valid ? fr * 0.5f : 0.0f;
    if (isX) { sXlo[i] = (int)lo; sHx[i] = wHi; sLx[i] = wLo; }
    else     { sYlo[i] = (int)lo; sHy[i] = wHi; sLy[i] = wLo; }
  }
  if (t == 0) sB = (int)rois[n * 5 + 0];
  __syncthreads();

  const int wave = t >> 6;       // 0..7
  const int lane = t & 63;
  const int half = lane >> 5;    // 0: x-lo corner, 1: x-hi corner
  const int sub = lane & 31;     // channel octet index
  const unsigned short* fb = ft + (size_t)sB * kHW * kC + sub * 8;
  unsigned int* s32 = (unsigned int*)sOut;

  for (int bin = wave; bin < kBins; bin += 8) {
    const int ph = bin / kPW, pw = bin % kPW;
    float acc[8] = {0.f, 0.f, 0.f, 0.f, 0.f, 0.f, 0.f, 0.f};
#pragma unroll
    for (int sy = 0; sy < kSR; ++sy) {
      const int iy = ph * kSR + sy;
      const int ylo = sYlo[iy];
      const float hy = sHy[iy], ly = sLy[iy];
#pragma unroll
      for (int sx = 0; sx < kSR; ++sx) {
        const int ix = pw * kSR + sx;
        const int xlo = sXlo[ix];
        const float hxs = half ? sLx[ix] : sHx[ix];   // this half's x-weight
        const float wTop = hy * hxs, wBot = ly * hxs;
        const unsigned short* p0 = fb + ((size_t)(ylo * kW + xlo + half)) * kC;
        const ushort8v v0 = *(const ushort8v*)(p0);            // row ylo
        const ushort8v v1 = *(const ushort8v*)(p0 + kW * kC);  // row ylo+1
#pragma unroll
        for (int k = 0; k < 8; ++k)
          acc[k] += wTop * b2f(v0[k]) + wBot * b2f(v1[k]);
      }
    }
    // merge the two corner-halves: butterfly across lane^32
#pragma unroll
    for (int k = 0; k < 8; ++k) acc[k] += __shfl_xor(acc[k], 32);
    // lane stores 2 u32 words (4 channels), picked by half
    const int kBase = half * 4;
    const unsigned int wA = (unsigned int)f2b(acc[kBase + 0]) |
                            ((unsigned int)f2b(acc[kBase + 1]) << 16);
    const unsigned int wB = (unsigned int)f2b(acc[kBase + 2]) |
                            ((unsigned int)f2b(acc[kBase + 3]) << 16);
    const int wIdx = bin * (kStrideE / 2) + sub * 4 + half * 2;
    s32[wIdx + 0] = wA;
    s32[wIdx + 1] = wB;
  }
  __syncthreads();

  // coalesced non-temporal float4 write of this ROI's (C,PH,PW) block
  float4v* ob4 = (float4v*)(out + (size_t)n * kOutPerRoi);
  for (int q = t; q < kOutPerRoi / 4; q += kThreads) {
    const int f = q * 4;
    const int c0 = (f + 0) / kBins, b0 = (f + 0) - c0 * kBins;
    const int c1 = (f + 1) / kBins, b1 = (f + 1) - c1 * kBins;
    const int c2 = (f + 2) / kBins, b2 = (f + 2) - c2 * kBins;
    const int c3 = (f + 3) / kBins, b3 = (f + 3) - c3 * kBins;
    float4v v;
    v.x = b2f(sOut[b0 * kStrideE + c0]);
    v.y = b2f(sOut[b1 * kStrideE + c1]);
    v.z = b2f(sOut[b2 * kStrideE + c2]);
    v.w = b2f(sOut[b3 * kStrideE + c3]);
    __builtin_nontemporal_store(v, &ob4[q]);
  }
}

extern "C" void kernel_launch(void* const* d_in, const int* in_sizes, int n_in,
                              void* d_out, int out_size, void* d_ws, size_t ws_size,
                              hipStream_t stream) {
  const float* feat = (const float*)d_in[0];
  const float* rois = (const float*)d_in[1];
  float* out = (float*)d_out;
  unsigned short* ft = (unsigned short*)d_ws;  // kB*kHW*kC*2 = 15.6 MB scratch

  hipLaunchKernelGGL(transpose_k, dim3(kHW / 32, kC / 64, kB), dim3(256), 0,
                     stream, feat, ft);
  hipLaunchKernelGGL(roialign_k, dim3(kN), dim3(kThreads), 0, stream, ft, rois, out);
}